// Round 1
// baseline (7039.855 us; speedup 1.0000x reference)
//
#include <hip/hip_runtime.h>
#include <math.h>

// Problem constants (from reference)
constexpr int kB  = 256;
constexpr int kT  = 512;
constexpr int kIN = 4;
constexpr int kM  = 3;
constexpr int kD  = 256;
constexpr int kNS = 64;
constexpr int kH  = 128;

__device__ __forceinline__ float sigmoidf_(float v) { return 1.0f / (1.0f + __expf(-v)); }

// One block per batch row; 256 threads; loop over all T timesteps internally.
// Thread tid owns (m, d=tid) rows of S/U/A for m=0..2 (D == blockDim.x == 256).
extern "C" __global__ void __launch_bounds__(256)
disc_kernel(const float* __restrict__ x,   const float* __restrict__ y,
            const float* __restrict__ U,   const float* __restrict__ S,
            const float* __restrict__ A,   const float* __restrict__ Wih,
            const float* __restrict__ Whh, const float* __restrict__ bih,
            const float* __restrict__ bhh, const float* __restrict__ Wd,
            const float* __restrict__ bd,
            float* __restrict__ out_o,  float* __restrict__ out_p)
{
    const int b    = blockIdx.x;
    const int tid  = threadIdx.x;
    const int lane = tid & 63;
    const int wid  = tid >> 6;

    __shared__ float sh_s[kNS];
    __shared__ float sh_h[kH];
    __shared__ float sh_hnew[kH];
    __shared__ float sh_K[kM * kD];        // 768
    __shared__ float sh_part[12 * 64];     // new_state partials (m,chunk) x n
    __shared__ float sh_ns[kM * kNS];      // 192
    __shared__ float sh_ghp[2 * 384];      // GRU k-half partials
    __shared__ float sh_gi[384];
    __shared__ float sh_gh[384];
    __shared__ float sh_enc[kM];
    __shared__ float sh_logit[kM];
    __shared__ float sh_gate[kM];
    __shared__ float sh_xt[4];
    __shared__ float sh_x2, sh_s2, sh_err;

    // ---- Per-thread persistent constants: U row + C = -0.5*(|U_md|^2 + |S_md|^2)
    const float4* S4 = reinterpret_cast<const float4*>(S);
    float4 Urow[3];
    float  Cc[3];
#pragma unroll
    for (int p = 0; p < 3; ++p) {
        const int row = p * kD + tid;
        float4 uv = reinterpret_cast<const float4*>(U)[row];   // U[(m*D+d)*4 ..]
        Urow[p] = uv;
        float s2sum = 0.f;
#pragma unroll
        for (int j = 0; j < 16; ++j) {
            float4 v = S4[row * 16 + j];
            s2sum += v.x*v.x + v.y*v.y + v.z*v.z + v.w*v.w;
        }
        Cc[p] = -0.5f * (uv.x*uv.x + uv.y*uv.y + uv.z*uv.z + uv.w*uv.w + s2sum);
    }

    // ---- Init carried state
    if (tid < kNS) sh_s[tid] = 0.f;
    if (tid < kH)  sh_h[tid] = 0.f;
    if (tid == 0) {
        sh_gate[0] = 0.3333f; sh_gate[1] = 0.3333f; sh_gate[2] = 0.3334f;
        sh_err = 1.0f;
        sh_s2  = 0.f;
        float4 xv = reinterpret_cast<const float4*>(x)[b * kT + 0];
        sh_xt[0] = xv.x; sh_xt[1] = xv.y; sh_xt[2] = xv.z; sh_xt[3] = xv.w;
        sh_x2 = xv.x*xv.x + xv.y*xv.y + xv.z*xv.z + xv.w*xv.w;
    }
    __syncthreads();

    for (int t = 0; t < kT; ++t) {
        // ================= Phase A: K[m, d=tid] ==========================
        // -0.5*du - 0.5*ds = -0.5*(x2+s2) + C[m,d] + x.U + s.S
        {
            const float scal = -0.5f * (sh_x2 + sh_s2);
            const float x0 = sh_xt[0], x1 = sh_xt[1], x2v = sh_xt[2], x3 = sh_xt[3];
            float dot[3] = {0.f, 0.f, 0.f};
            const float4* s4l = reinterpret_cast<const float4*>(sh_s);
#pragma unroll 4
            for (int j = 0; j < 16; ++j) {
                float4 sv = s4l[j];              // LDS broadcast (same addr all lanes)
#pragma unroll
                for (int p = 0; p < 3; ++p) {
                    float4 Sv = S4[(p * kD + tid) * 16 + j];
                    dot[p] += sv.x*Sv.x + sv.y*Sv.y + sv.z*Sv.z + sv.w*Sv.w;
                }
            }
#pragma unroll
            for (int p = 0; p < 3; ++p) {
                float xu = x0*Urow[p].x + x1*Urow[p].y + x2v*Urow[p].z + x3*Urow[p].w;
                sh_K[p * kD + tid] = __expf(scal + Cc[p] + xu + dot[p]);
            }
        }
        __syncthreads();                                    // (1)

        // ====== Phase B: new_state partials (wave handles 3 (m,chunk) tasks) ======
        {
#pragma unroll
            for (int e = 0; e < 3; ++e) {
                const int q = wid * 3 + e;      // q in [0,12)
                const int m = q >> 2, c = q & 3;
                const float* Ab = A + (m * kD + c * 64) * kNS + lane;   // coalesced in lane
                const float* Kb = sh_K + m * kD + c * 64;
                float acc = 0.f;
#pragma unroll 8
                for (int dd = 0; dd < 64; ++dd)
                    acc += Kb[dd] * Ab[dd * kNS];
                sh_part[q * 64 + lane] = acc;
            }
            // encoded[m] = max_d K[m,d]  (waves 0..2)
            if (wid < 3) {
                const int m = wid;
                float mx = fmaxf(fmaxf(sh_K[m*kD + lane],      sh_K[m*kD + 64 + lane]),
                                 fmaxf(sh_K[m*kD + 128 + lane], sh_K[m*kD + 192 + lane]));
#pragma unroll
                for (int o = 32; o > 0; o >>= 1) mx = fmaxf(mx, __shfl_xor(mx, o, 64));
                if (lane == 0) sh_enc[m] = mx;
            }
        }
        __syncthreads();                                    // (2)

        // ====== Phase C: ns reduce + GRU k-partials ======
        if (tid < 192) {
            const int m = tid >> 6, n = tid & 63;
            sh_ns[m * 64 + n] = sh_part[(4*m+0)*64 + n] + sh_part[(4*m+1)*64 + n]
                              + sh_part[(4*m+2)*64 + n] + sh_part[(4*m+3)*64 + n];
        }
        {
            const int jl = tid & 127, kh = tid >> 7;
            float a0 = 0.f, a1 = 0.f, a2 = 0.f;
            const int k0 = kh * 64;
#pragma unroll 8
            for (int k = k0; k < k0 + 64; ++k) {
                const float hk = sh_h[k];                       // LDS broadcast
                const float* Wr = Whh + k * 384 + jl;           // coalesced in jl
                a0 += hk * Wr[0];
                a1 += hk * Wr[128];
                a2 += hk * Wr[256];
            }
            sh_ghp[kh*384 + jl]       = a0;
            sh_ghp[kh*384 + 128 + jl] = a1;
            sh_ghp[kh*384 + 256 + jl] = a2;
        }
        __syncthreads();                                    // (3)

        // ====== Phase D1: gi/gh combine ======
        {
            const float i0 = sh_enc[0], i1 = sh_enc[1], i2 = sh_enc[2], i3 = sh_err;
            for (int j = tid; j < 384; j += 256) {
                sh_gh[j] = sh_ghp[j] + sh_ghp[384 + j] + bhh[j];
                sh_gi[j] = bih[j] + i0*Wih[j] + i1*Wih[384 + j]
                                  + i2*Wih[768 + j] + i3*Wih[1152 + j];
            }
        }
        __syncthreads();                                    // (4)

        // ====== Phase D2: GRU elementwise ======
        if (tid < kH) {
            const float r  = sigmoidf_(sh_gi[tid]       + sh_gh[tid]);
            const float z  = sigmoidf_(sh_gi[128 + tid] + sh_gh[128 + tid]);
            const float nn = tanhf(sh_gi[256 + tid] + r * sh_gh[256 + tid]);
            sh_hnew[tid] = (1.f - z) * nn + z * sh_h[tid];
        }
        __syncthreads();                                    // (5)

        // ====== Phase D3: gate logits (h_new[:127] @ Wd + bd) ======
        if (wid < 3) {
            const int m = wid;
            float a = sh_hnew[lane] * Wd[lane * 3 + m];
            if (lane < 63) a += sh_hnew[64 + lane] * Wd[(64 + lane) * 3 + m];
#pragma unroll
            for (int o = 32; o > 0; o >>= 1) a += __shfl_xor(a, o, 64);
            if (lane == 0) sh_logit[m] = a + bd[m];
        }
        __syncthreads();                                    // (6)

        // ====== Phase D4: softmax / theta / gate blend / penalty (thread 0) ======
        if (tid == 0) {
            const float l0 = sh_logit[0], l1 = sh_logit[1], l2 = sh_logit[2];
            const float mx = fmaxf(l0, fmaxf(l1, l2));
            const float e0 = __expf(l0 - mx), e1 = __expf(l1 - mx), e2 = __expf(l2 - mx);
            const float inv = 1.f / (e0 + e1 + e2);
            const float theta = sigmoidf_(sh_hnew[127]);
            const float omt = 1.f - theta;
            const float g0 = e0*inv*theta + sh_gate[0]*omt;
            const float g1 = e1*inv*theta + sh_gate[1]*omt;
            const float g2 = e2*inv*theta + sh_gate[2]*omt;
            sh_gate[0] = g0; sh_gate[1] = g1; sh_gate[2] = g2;
            out_p[b * kT + t] = g0*(1.f-g0) + g1*(1.f-g1) + g2*(1.f-g2);
        }
        __syncthreads();                                    // (7)

        // ====== Phase E: s_new, outputs, next-step prep ======
        if (wid == 0) {
            const float g0 = sh_gate[0], g1 = sh_gate[1], g2 = sh_gate[2];
            const float sn = g0*sh_ns[lane] + g1*sh_ns[64 + lane] + g2*sh_ns[128 + lane];
            sh_s[lane] = sn;
            if (lane == 63) {
                out_o[b * kT + t] = sn;           // pred = s_new[63]
                sh_err = sn - y[b * kT + t];
            }
            float ss = sn * sn;
#pragma unroll
            for (int o = 32; o > 0; o >>= 1) ss += __shfl_xor(ss, o, 64);
            if (lane == 0) sh_s2 = ss;
        }
        if (wid == 1 && lane == 0 && (t + 1) < kT) {
            float4 xv = reinterpret_cast<const float4*>(x)[b * kT + t + 1];
            sh_xt[0] = xv.x; sh_xt[1] = xv.y; sh_xt[2] = xv.z; sh_xt[3] = xv.w;
            sh_x2 = xv.x*xv.x + xv.y*xv.y + xv.z*xv.z + xv.w*xv.w;
        }
        if (tid >= 128) sh_h[tid - 128] = sh_hnew[tid - 128];
        __syncthreads();                                    // (8)
    }
}

extern "C" void kernel_launch(void* const* d_in, const int* in_sizes, int n_in,
                              void* d_out, int out_size, void* d_ws, size_t ws_size,
                              hipStream_t stream)
{
    const float* x   = (const float*)d_in[0];
    const float* y   = (const float*)d_in[1];
    const float* U   = (const float*)d_in[2];
    const float* S   = (const float*)d_in[3];
    const float* A   = (const float*)d_in[4];
    const float* Wih = (const float*)d_in[5];
    const float* Whh = (const float*)d_in[6];
    const float* bih = (const float*)d_in[7];
    const float* bhh = (const float*)d_in[8];
    const float* Wd  = (const float*)d_in[9];
    const float* bd  = (const float*)d_in[10];

    float* out_o = (float*)d_out;            // (B, T) preds
    float* out_p = out_o + kB * kT;          // (B, T, 1) penalties

    hipLaunchKernelGGL(disc_kernel, dim3(kB), dim3(256), 0, stream,
                       x, y, U, S, A, Wih, Whh, bih, bhh, Wd, bd, out_o, out_p);
}